// Round 1
// baseline (817.289 us; speedup 1.0000x reference)
//
#include <hip/hip_runtime.h>
#include <stdint.h>

typedef unsigned short u16;
typedef unsigned int u32;
typedef __attribute__((ext_vector_type(8))) short bf16x8;   // 8 bf16 (4 VGPRs)
typedef __attribute__((ext_vector_type(4))) float f32x4;    // MFMA C/D

#define G_AS __attribute__((address_space(1)))
#define L_AS __attribute__((address_space(3)))

__device__ __forceinline__ void gload16(const void* g, void* l) {
  __builtin_amdgcn_global_load_lds((const G_AS u32*)g, (L_AS u32*)l, 16, 0, 0);
}

// ---------------- static ragged-group metadata (compile-time) ----------------
// M = {4096,2048,1024,3072,2048,1024,1536,1584}, K=N=2048
// a_off (== c_off) cumulative M*2048; b_off = g*2048*2048.

// ---------------- prep: split A into bf16 hi/lo, pre-swizzled ----------------
// Storage layout per row: within each 64-elem kt segment, 16B chunk c stored at
// c ^ (row&7)  -> linear global_load_lds lands "swizzled" in LDS; ds_read
// applies the same XOR -> conflict-free fragment reads.
__global__ __launch_bounds__(256) void prep_a(const float* __restrict__ A,
                                              u16* __restrict__ Ah, u16* __restrict__ Al) {
  long i = (long)blockIdx.x * 256 + threadIdx.x;   // one 8-elem chunk per thread
  if (i >= 4206592L) return;                       // 33,652,736 / 8
  long base = i << 3;
  long row = base >> 11;
  int k = (int)(base & 2047);
  int cs = ((k >> 3) & 7) ^ ((int)row & 7);
  long dest = (row << 11) + (k & 1984) + (cs << 3);
  const float4* ap = (const float4*)(A + base);
  float4 v0 = ap[0], v1 = ap[1];
  float x[8] = {v0.x, v0.y, v0.z, v0.w, v1.x, v1.y, v1.z, v1.w};
  union { u16 u[8]; uint4 v; } H, L;
#pragma unroll
  for (int e = 0; e < 8; ++e) {
    u32 u = __float_as_uint(x[e]);
    H.u[e] = (u16)(u >> 16);                                   // truncation split
    float r = x[e] - __uint_as_float(u & 0xffff0000u);         // exact residual
    L.u[e] = (u16)(__float_as_uint(r) >> 16);
  }
  *(uint4*)(Ah + dest) = H.v;
  *(uint4*)(Al + dest) = L.v;
}

// ------- prep: B -> B^T (per group), split hi/lo bf16, pre-swizzled ---------
__global__ __launch_bounds__(256) void prep_b(const float* __restrict__ B,
                                              u16* __restrict__ Bh, u16* __restrict__ Bl) {
  __shared__ float tile[64][65];
  int bid = blockIdx.x;
  int g = bid >> 10;                 // 1024 64x64 tiles per 2048x2048 group
  int tt = bid & 1023;
  int tk = tt >> 5, tn = tt & 31;
  long gb = (long)g * 4194304L;
  int k0 = tk << 6, n0 = tn << 6;
  int t = threadIdx.x;
#pragma unroll
  for (int i = 0; i < 4; ++i) {      // coalesced read of 64x64 fp32 tile
    int r = (t >> 4) + (i << 4);
    float4 v = *(const float4*)(B + gb + (long)(k0 + r) * 2048 + n0 + ((t & 15) << 2));
    int c4 = (t & 15) << 2;
    tile[r][c4] = v.x; tile[r][c4 + 1] = v.y; tile[r][c4 + 2] = v.z; tile[r][c4 + 3] = v.w;
  }
  __syncthreads();
#pragma unroll
  for (int p = 0; p < 2; ++p) {      // transposed, split, swizzled write
    int n = (t >> 3) + (p << 5);
    int c = t & 7;
    union { u16 u[8]; uint4 v; } H, L;
#pragma unroll
    for (int j = 0; j < 8; ++j) {
      float x = tile[(c << 3) + j][n];
      u32 u = __float_as_uint(x);
      H.u[j] = (u16)(u >> 16);
      float r = x - __uint_as_float(u & 0xffff0000u);
      L.u[j] = (u16)(__float_as_uint(r) >> 16);
    }
    long dest = gb + (long)(n0 + n) * 2048 + k0 + ((long)(c ^ ((n0 + n) & 7)) << 3);
    *(uint4*)(Bh + dest) = H.v;
    *(uint4*)(Bl + dest) = L.v;
  }
}

// ---------------- main bf16x3 grouped GEMM, 128x128 tile -------------------
// 4 waves (2x2), each wave 64x64 via 4x4 fragments of mfma_f32_16x16x32_bf16.
// acc += Ahi*Bhi + Ahi*Blo + Alo*Bhi  (3 MFMA per fragment pair).
template <bool PRE_A>
__global__ __launch_bounds__(256, 2) void gemm3(
    const u16* __restrict__ Ah, const u16* __restrict__ Al, const float* __restrict__ Af,
    const u16* __restrict__ Bh, const u16* __restrict__ Bl,
    const float* __restrict__ Cin, float* __restrict__ Out,
    const float* __restrict__ alpha, const float* __restrict__ beta) {
  const int mt_cum[9] = {0, 32, 48, 56, 80, 96, 104, 116, 129};
  const int Ms[8] = {4096, 2048, 1024, 3072, 2048, 1024, 1536, 1584};
  const long a_off[8] = {0L, 8388608L, 12582912L, 14680064L,
                         20971520L, 25165824L, 27262976L, 30408704L};

  __shared__ u16 lds[32768];  // 64KB: Ah[0:8K) Al[8K:16K) Bh[16K:24K) Bl[24K:32K) (u16 idx)

  int bid = blockIdx.x;
  int mtg = bid >> 4, nt = bid & 15;
  int g = 0;
#pragma unroll
  for (int i = 1; i < 8; ++i) if (mtg >= mt_cum[i]) g = i;
  int m0 = (mtg - mt_cum[g]) << 7;
  int Mg = Ms[g];
  long abase = a_off[g];
  long bbase = (long)g * 4194304L + ((long)(nt << 7)) * 2048L;

  int t = threadIdx.x;
  int lane = t & 63, wv = t >> 6;
  int wrow = (wv >> 1) << 6, wcol = (wv & 1) << 6;
  int hi4 = lane >> 4, l15 = lane & 15;

  f32x4 acc[4][4];
#pragma unroll
  for (int mi = 0; mi < 4; ++mi)
#pragma unroll
    for (int ni = 0; ni < 4; ++ni) acc[mi][ni] = 0;

  int srow = t >> 3;        // staging row (per round of 32 rows)
  int schunk = t & 7;       // stored 16B chunk index

  for (int kt = 0; kt < 32; ++kt) {
    __syncthreads();
    long koff = ((long)kt << 6) + (schunk << 3);
    if constexpr (PRE_A) {
#pragma unroll
      for (int rr = 0; rr < 4; ++rr) {
        int tr = (rr << 5) + srow;
        int ar = m0 + tr; ar = ar < Mg ? ar : (Mg - 1);   // clamp partial tile
        long ga = abase + (long)ar * 2048 + koff;
        long gbb = bbase + (long)tr * 2048 + koff;
        int lo = (rr << 12) + (t << 4);                    // linear LDS bytes
        gload16(Ah + ga, (char*)lds + lo);
        gload16(Al + ga, (char*)lds + 16384 + lo);
        gload16(Bh + gbb, (char*)lds + 32768 + lo);
        gload16(Bl + gbb, (char*)lds + 49152 + lo);
      }
    } else {
#pragma unroll
      for (int rr = 0; rr < 4; ++rr) {
        int tr = (rr << 5) + srow;
        long gbb = bbase + (long)tr * 2048 + koff;
        int lo = (rr << 12) + (t << 4);
        gload16(Bh + gbb, (char*)lds + 32768 + lo);
        gload16(Bl + gbb, (char*)lds + 49152 + lo);
      }
      int rbase = (t >> 2) & 15;
      int f4 = (t & 3) + ((t >> 6) << 2);                  // 0..15 float4 slot
#pragma unroll
      for (int rr = 0; rr < 8; ++rr) {
        int tr = (rr << 4) + rbase;
        int ar = m0 + tr; ar = ar < Mg ? ar : (Mg - 1);
        float4 v = *(const float4*)(Af + abase + (long)ar * 2048 + ((long)kt << 6) + (f4 << 2));
        float x[4] = {v.x, v.y, v.z, v.w};
        union { u16 u[4]; uint2 w; } Hh, Ll;
#pragma unroll
        for (int e = 0; e < 4; ++e) {
          u32 u = __float_as_uint(x[e]);
          Hh.u[e] = (u16)(u >> 16);
          float r = x[e] - __uint_as_float(u & 0xffff0000u);
          Ll.u[e] = (u16)(__float_as_uint(r) >> 16);
        }
        int db = (tr << 7) + (((f4 >> 1) ^ (tr & 7)) << 4) + ((f4 & 1) << 3); // swizzled bytes
        *(uint2*)((char*)lds + db) = Hh.w;
        *(uint2*)((char*)lds + 16384 + db) = Ll.w;
      }
    }
    __syncthreads();
#pragma unroll
    for (int k2 = 0; k2 < 2; ++k2) {
      int cc = (k2 << 2) + hi4;                            // logical 16B chunk
      bf16x8 ah[4], al[4], bh[4], bl[4];
#pragma unroll
      for (int mi = 0; mi < 4; ++mi) {
        int r = wrow + (mi << 4) + l15;
        int off = (r << 6) + ((cc ^ (r & 7)) << 3);        // u16 units, swizzled
        ah[mi] = *(const bf16x8*)(lds + off);
        al[mi] = *(const bf16x8*)(lds + 8192 + off);
      }
#pragma unroll
      for (int ni = 0; ni < 4; ++ni) {
        int r = wcol + (ni << 4) + l15;
        int off = (r << 6) + ((cc ^ (r & 7)) << 3);
        bh[ni] = *(const bf16x8*)(lds + 16384 + off);
        bl[ni] = *(const bf16x8*)(lds + 24576 + off);
      }
#pragma unroll
      for (int mi = 0; mi < 4; ++mi)
#pragma unroll
        for (int ni = 0; ni < 4; ++ni) {
          acc[mi][ni] = __builtin_amdgcn_mfma_f32_16x16x32_bf16(ah[mi], bh[ni], acc[mi][ni], 0, 0, 0);
          acc[mi][ni] = __builtin_amdgcn_mfma_f32_16x16x32_bf16(ah[mi], bl[ni], acc[mi][ni], 0, 0, 0);
          acc[mi][ni] = __builtin_amdgcn_mfma_f32_16x16x32_bf16(al[mi], bh[ni], acc[mi][ni], 0, 0, 0);
        }
    }
  }
  // epilogue: out = alpha*acc + beta*C   (C/D: row = 4*(lane>>4)+j, col = lane&15)
  float alg = alpha[g], beg = beta[g];
  long cb = abase + ((long)(nt << 7));
#pragma unroll
  for (int mi = 0; mi < 4; ++mi) {
#pragma unroll
    for (int j = 0; j < 4; ++j) {
      int row = m0 + wrow + (mi << 4) + (hi4 << 2) + j;
      if (row < Mg) {
        long rb = cb + (long)row * 2048;
#pragma unroll
        for (int ni = 0; ni < 4; ++ni) {
          long idx = rb + wcol + (ni << 4) + l15;
          Out[idx] = alg * acc[mi][ni][j] + beg * Cin[idx];
        }
      }
    }
  }
}

// ---------------- fallback: naive fp32 tiled GEMM (ws too small) ------------
__global__ __launch_bounds__(256) void gemm_naive(
    const float* __restrict__ A, const float* __restrict__ B,
    const float* __restrict__ Cin, float* __restrict__ Out,
    const float* __restrict__ alpha, const float* __restrict__ beta) {
  const int mt_cum[9] = {0, 64, 96, 112, 160, 192, 208, 232, 257};
  const int Ms[8] = {4096, 2048, 1024, 3072, 2048, 1024, 1536, 1584};
  const long a_off[8] = {0L, 8388608L, 12582912L, 14680064L,
                         20971520L, 25165824L, 27262976L, 30408704L};
  __shared__ float As[16][65];
  __shared__ float Bs[16][68];
  int bid = blockIdx.x;
  int mtg = bid >> 5, nt = bid & 31;
  int g = 0;
#pragma unroll
  for (int i = 1; i < 8; ++i) if (mtg >= mt_cum[i]) g = i;
  int m0 = (mtg - mt_cum[g]) << 6, n0 = nt << 6;
  int Mg = Ms[g];
  int t = threadIdx.x;
  int ty = t >> 4, tx = t & 15;
  float acc[4][4] = {};
  for (int k0 = 0; k0 < 2048; k0 += 16) {
    __syncthreads();
    {
      int m = t >> 2, ks = (t & 3) << 2;
      int ar = m0 + m; ar = ar < Mg ? ar : (Mg - 1);
      float4 v = *(const float4*)(A + a_off[g] + (long)ar * 2048 + k0 + ks);
      As[ks][m] = v.x; As[ks + 1][m] = v.y; As[ks + 2][m] = v.z; As[ks + 3][m] = v.w;
    }
    {
      int k = t >> 4, n4 = (t & 15) << 2;
      float4 v = *(const float4*)(B + (long)g * 4194304L + (long)(k0 + k) * 2048 + n0 + n4);
      *(float4*)&Bs[k][n4] = v;
    }
    __syncthreads();
#pragma unroll
    for (int k = 0; k < 16; ++k) {
      float a[4], b[4];
#pragma unroll
      for (int i = 0; i < 4; ++i) a[i] = As[k][(ty << 2) + i];
#pragma unroll
      for (int j = 0; j < 4; ++j) b[j] = Bs[k][(tx << 2) + j];
#pragma unroll
      for (int i = 0; i < 4; ++i)
#pragma unroll
        for (int j = 0; j < 4; ++j) acc[i][j] += a[i] * b[j];
    }
  }
  float alg = alpha[g], beg = beta[g];
#pragma unroll
  for (int i = 0; i < 4; ++i) {
    int row = m0 + (ty << 2) + i;
    if (row < Mg) {
#pragma unroll
      for (int j = 0; j < 4; ++j) {
        long idx = a_off[g] + (long)row * 2048 + n0 + (tx << 2) + j;
        Out[idx] = alg * acc[i][j] + beg * Cin[idx];
      }
    }
  }
}

extern "C" void kernel_launch(void* const* d_in, const int* in_sizes, int n_in,
                              void* d_out, int out_size, void* d_ws, size_t ws_size,
                              hipStream_t stream) {
  const float* A = (const float*)d_in[0];
  const float* B = (const float*)d_in[1];
  const float* C = (const float*)d_in[2];
  const float* alpha = (const float*)d_in[3];
  const float* beta = (const float*)d_in[4];
  float* Out = (float*)d_out;

  // ws tiers (ws_size constant across calls -> deterministic, graph-safe)
  if (ws_size >= 268828672ull) {
    u16* ws16 = (u16*)d_ws;
    u16* Bh = ws16;                  // 33,554,432 u16
    u16* Bl = ws16 + 33554432;
    u16* Ah = ws16 + 67108864;       // 33,652,736 u16
    u16* Al = ws16 + 100761600;
    prep_a<<<16432, 256, 0, stream>>>(A, Ah, Al);
    prep_b<<<8192, 256, 0, stream>>>(B, Bh, Bl);
    gemm3<true><<<2064, 256, 0, stream>>>(Ah, Al, nullptr, Bh, Bl, C, Out, alpha, beta);
  } else if (ws_size >= 134217728ull) {
    u16* ws16 = (u16*)d_ws;
    u16* Bh = ws16;
    u16* Bl = ws16 + 33554432;
    prep_b<<<8192, 256, 0, stream>>>(B, Bh, Bl);
    gemm3<false><<<2064, 256, 0, stream>>>(nullptr, nullptr, A, Bh, Bl, C, Out, alpha, beta);
  } else {
    gemm_naive<<<8224, 256, 0, stream>>>(A, B, C, Out, alpha, beta);
  }
}

// Round 4
// 807.778 us; speedup vs baseline: 1.0118x; 1.0118x over previous
//
#include <hip/hip_runtime.h>
#include <stdint.h>

typedef unsigned short u16;
typedef unsigned int u32;
typedef __attribute__((ext_vector_type(8))) short bf16x8;   // 8 bf16 (4 VGPRs)
typedef __attribute__((ext_vector_type(4))) float f32x4;    // MFMA C/D

#define G_AS __attribute__((address_space(1)))
#define L_AS __attribute__((address_space(3)))

__device__ __forceinline__ void gload16(const void* g, void* l) {
  __builtin_amdgcn_global_load_lds((const G_AS u32*)g, (L_AS u32*)l, 16, 0, 0);
}

// ---------------- static ragged-group metadata (compile-time) ----------------
// M = {4096,2048,1024,3072,2048,1024,1536,1584}, K=N=2048
// a_off (== c_off) cumulative M*2048; b_off = g*2048*2048.

// ---------------- fused prep ------------------------------------------------
// bid < 2048   : B-part. 64k x 256n tiles (256/group x 8 groups). Reads B with
//                1KB-contiguous rows, LDS transpose (padded 257, conflict-free
//                column reads), writes B^T split hi/lo bf16, pre-swizzled:
//                16B chunk c of each 64-elem k-segment stored at c ^ (n&7).
// bid >= 2048  : A-part. Pure stream: split A into bf16 hi/lo, same per-row
//                swizzle (c ^ (row&7)), 8 elems per thread.
// Swizzle invariant: linear global_load_lds in gemm3 lands "pre-swizzled" in
// LDS; the fragment ds_read applies the same XOR -> conflict-free.
__global__ __launch_bounds__(256) void prep_fused(
    const float* __restrict__ A, u16* __restrict__ Ah, u16* __restrict__ Al,
    const float* __restrict__ B, u16* __restrict__ Bh, u16* __restrict__ Bl) {
  __shared__ float tile[64][257];
  int bid = blockIdx.x;
  int t = threadIdx.x;
  if (bid < 2048) {
    int g = bid >> 8;                  // 8 groups x 256 tiles
    int tt = bid & 255;
    int tk = tt >> 3, tn = tt & 7;     // 32 k-tiles x 8 n-tiles
    long gb = (long)g * 4194304L;
    int k0 = tk << 6, n0 = tn << 8;
    // load 64 rows x 256 cols fp32; each row = 1KB contiguous per 64 lanes
#pragma unroll
    for (int i = 0; i < 16; ++i) {
      int chunk = (i << 8) + t;        // 64 float4-chunks per row
      int r = chunk >> 6;
      int c4 = (chunk & 63) << 2;
      float4 v = *(const float4*)(B + gb + (long)(k0 + r) * 2048 + n0 + c4);
      tile[r][c4] = v.x; tile[r][c4 + 1] = v.y;
      tile[r][c4 + 2] = v.z; tile[r][c4 + 3] = v.w;
    }
    __syncthreads();
    // transposed, split, swizzled write: 8 passes x (8 n-rows x 8 chunks)
    int c = t & 7;
#pragma unroll
    for (int p = 0; p < 8; ++p) {
      int nl = (t >> 3) + (p << 5);
      int n = n0 + nl;
      union { u16 u[8]; uint4 v; } H, L;
#pragma unroll
      for (int j = 0; j < 8; ++j) {
        float x = tile[(c << 3) + j][nl];
        u32 u = __float_as_uint(x);
        H.u[j] = (u16)(u >> 16);                               // truncation split
        float r = x - __uint_as_float(u & 0xffff0000u);        // exact residual
        L.u[j] = (u16)(__float_as_uint(r) >> 16);
      }
      long dest = gb + (long)n * 2048 + k0 + ((long)(c ^ (n & 7)) << 3);
      *(uint4*)(Bh + dest) = H.v;
      *(uint4*)(Bl + dest) = L.v;
    }
  } else {
    long i = (long)(bid - 2048) * 256 + t;   // one 8-elem chunk per thread
    if (i >= 4206592L) return;               // 33,652,736 / 8
    long base = i << 3;
    long row = base >> 11;
    int k = (int)(base & 2047);
    int cs = ((k >> 3) & 7) ^ ((int)row & 7);
    long dest = (row << 11) + (k & 1984) + (cs << 3);
    const float4* ap = (const float4*)(A + base);
    float4 v0 = ap[0], v1 = ap[1];
    float x[8] = {v0.x, v0.y, v0.z, v0.w, v1.x, v1.y, v1.z, v1.w};
    union { u16 u[8]; uint4 v; } H, L;
#pragma unroll
    for (int e = 0; e < 8; ++e) {
      u32 u = __float_as_uint(x[e]);
      H.u[e] = (u16)(u >> 16);
      float r = x[e] - __uint_as_float(u & 0xffff0000u);
      L.u[e] = (u16)(__float_as_uint(r) >> 16);
    }
    *(uint4*)(Ah + dest) = H.v;
    *(uint4*)(Al + dest) = L.v;
  }
}

// ---------------- main bf16x3 grouped GEMM, 128x128 tile -------------------
// 4 waves (2x2), each wave 64x64 via 4x4 fragments of mfma_f32_16x16x32_bf16.
// acc += Ahi*Bhi + Ahi*Blo + Alo*Bhi  (3 MFMA per fragment pair).
// UNCHANGED from R1 (control: 472 us, MfmaUtil 38.8%, 0 bank conflicts).
template <bool PRE_A>
__global__ __launch_bounds__(256, 2) void gemm3(
    const u16* __restrict__ Ah, const u16* __restrict__ Al, const float* __restrict__ Af,
    const u16* __restrict__ Bh, const u16* __restrict__ Bl,
    const float* __restrict__ Cin, float* __restrict__ Out,
    const float* __restrict__ alpha, const float* __restrict__ beta) {
  const int mt_cum[9] = {0, 32, 48, 56, 80, 96, 104, 116, 129};
  const int Ms[8] = {4096, 2048, 1024, 3072, 2048, 1024, 1536, 1584};
  const long a_off[8] = {0L, 8388608L, 12582912L, 14680064L,
                         20971520L, 25165824L, 27262976L, 30408704L};

  __shared__ u16 lds[32768];  // 64KB: Ah[0:8K) Al[8K:16K) Bh[16K:24K) Bl[24K:32K) (u16 idx)

  int bid = blockIdx.x;
  int mtg = bid >> 4, nt = bid & 15;
  int g = 0;
#pragma unroll
  for (int i = 1; i < 8; ++i) if (mtg >= mt_cum[i]) g = i;
  int m0 = (mtg - mt_cum[g]) << 7;
  int Mg = Ms[g];
  long abase = a_off[g];
  long bbase = (long)g * 4194304L + ((long)(nt << 7)) * 2048L;

  int t = threadIdx.x;
  int lane = t & 63, wv = t >> 6;
  int wrow = (wv >> 1) << 6, wcol = (wv & 1) << 6;
  int hi4 = lane >> 4, l15 = lane & 15;

  f32x4 acc[4][4];
#pragma unroll
  for (int mi = 0; mi < 4; ++mi)
#pragma unroll
    for (int ni = 0; ni < 4; ++ni) acc[mi][ni] = 0;

  int srow = t >> 3;        // staging row (per round of 32 rows)
  int schunk = t & 7;       // stored 16B chunk index

  for (int kt = 0; kt < 32; ++kt) {
    __syncthreads();
    long koff = ((long)kt << 6) + (schunk << 3);
    if constexpr (PRE_A) {
#pragma unroll
      for (int rr = 0; rr < 4; ++rr) {
        int tr = (rr << 5) + srow;
        int ar = m0 + tr; ar = ar < Mg ? ar : (Mg - 1);   // clamp partial tile
        long ga = abase + (long)ar * 2048 + koff;
        long gbb = bbase + (long)tr * 2048 + koff;
        int lo = (rr << 12) + (t << 4);                    // linear LDS bytes
        gload16(Ah + ga, (char*)lds + lo);
        gload16(Al + ga, (char*)lds + 16384 + lo);
        gload16(Bh + gbb, (char*)lds + 32768 + lo);
        gload16(Bl + gbb, (char*)lds + 49152 + lo);
      }
    } else {
#pragma unroll
      for (int rr = 0; rr < 4; ++rr) {
        int tr = (rr << 5) + srow;
        long gbb = bbase + (long)tr * 2048 + koff;
        int lo = (rr << 12) + (t << 4);
        gload16(Bh + gbb, (char*)lds + 32768 + lo);
        gload16(Bl + gbb, (char*)lds + 49152 + lo);
      }
      int rbase = (t >> 2) & 15;
      int f4 = (t & 3) + ((t >> 6) << 2);                  // 0..15 float4 slot
#pragma unroll
      for (int rr = 0; rr < 8; ++rr) {
        int tr = (rr << 4) + rbase;
        int ar = m0 + tr; ar = ar < Mg ? ar : (Mg - 1);
        float4 v = *(const float4*)(Af + abase + (long)ar * 2048 + ((long)kt << 6) + (f4 << 2));
        float x[4] = {v.x, v.y, v.z, v.w};
        union { u16 u[4]; uint2 w; } Hh, Ll;
#pragma unroll
        for (int e = 0; e < 4; ++e) {
          u32 u = __float_as_uint(x[e]);
          Hh.u[e] = (u16)(u >> 16);
          float r = x[e] - __uint_as_float(u & 0xffff0000u);
          Ll.u[e] = (u16)(__float_as_uint(r) >> 16);
        }
        int db = (tr << 7) + (((f4 >> 1) ^ (tr & 7)) << 4) + ((f4 & 1) << 3); // swizzled bytes
        *(uint2*)((char*)lds + db) = Hh.w;
        *(uint2*)((char*)lds + 16384 + db) = Ll.w;
      }
    }
    __syncthreads();
#pragma unroll
    for (int k2 = 0; k2 < 2; ++k2) {
      int cc = (k2 << 2) + hi4;                            // logical 16B chunk
      bf16x8 ah[4], al[4], bh[4], bl[4];
#pragma unroll
      for (int mi = 0; mi < 4; ++mi) {
        int r = wrow + (mi << 4) + l15;
        int off = (r << 6) + ((cc ^ (r & 7)) << 3);        // u16 units, swizzled
        ah[mi] = *(const bf16x8*)(lds + off);
        al[mi] = *(const bf16x8*)(lds + 8192 + off);
      }
#pragma unroll
      for (int ni = 0; ni < 4; ++ni) {
        int r = wcol + (ni << 4) + l15;
        int off = (r << 6) + ((cc ^ (r & 7)) << 3);
        bh[ni] = *(const bf16x8*)(lds + 16384 + off);
        bl[ni] = *(const bf16x8*)(lds + 24576 + off);
      }
#pragma unroll
      for (int mi = 0; mi < 4; ++mi)
#pragma unroll
        for (int ni = 0; ni < 4; ++ni) {
          acc[mi][ni] = __builtin_amdgcn_mfma_f32_16x16x32_bf16(ah[mi], bh[ni], acc[mi][ni], 0, 0, 0);
          acc[mi][ni] = __builtin_amdgcn_mfma_f32_16x16x32_bf16(ah[mi], bl[ni], acc[mi][ni], 0, 0, 0);
          acc[mi][ni] = __builtin_amdgcn_mfma_f32_16x16x32_bf16(al[mi], bh[ni], acc[mi][ni], 0, 0, 0);
        }
    }
  }
  // epilogue: out = alpha*acc + beta*C   (C/D: row = 4*(lane>>4)+j, col = lane&15)
  float alg = alpha[g], beg = beta[g];
  long cb = abase + ((long)(nt << 7));
#pragma unroll
  for (int mi = 0; mi < 4; ++mi) {
#pragma unroll
    for (int j = 0; j < 4; ++j) {
      int row = m0 + wrow + (mi << 4) + (hi4 << 2) + j;
      if (row < Mg) {
        long rb = cb + (long)row * 2048;
#pragma unroll
        for (int ni = 0; ni < 4; ++ni) {
          long idx = rb + wcol + (ni << 4) + l15;
          Out[idx] = alg * acc[mi][ni][j] + beg * Cin[idx];
        }
      }
    }
  }
}

// ---------------- fallback: naive fp32 tiled GEMM (ws too small) ------------
__global__ __launch_bounds__(256) void gemm_naive(
    const float* __restrict__ A, const float* __restrict__ B,
    const float* __restrict__ Cin, float* __restrict__ Out,
    const float* __restrict__ alpha, const float* __restrict__ beta) {
  const int mt_cum[9] = {0, 64, 96, 112, 160, 192, 208, 232, 257};
  const int Ms[8] = {4096, 2048, 1024, 3072, 2048, 1024, 1536, 1584};
  const long a_off[8] = {0L, 8388608L, 12582912L, 14680064L,
                         20971520L, 25165824L, 27262976L, 30408704L};
  __shared__ float As[16][65];
  __shared__ float Bs[16][68];
  int bid = blockIdx.x;
  int mtg = bid >> 5, nt = bid & 31;
  int g = 0;
#pragma unroll
  for (int i = 1; i < 8; ++i) if (mtg >= mt_cum[i]) g = i;
  int m0 = (mtg - mt_cum[g]) << 6, n0 = nt << 6;
  int Mg = Ms[g];
  int t = threadIdx.x;
  int ty = t >> 4, tx = t & 15;
  float acc[4][4] = {};
  for (int k0 = 0; k0 < 2048; k0 += 16) {
    __syncthreads();
    {
      int m = t >> 2, ks = (t & 3) << 2;
      int ar = m0 + m; ar = ar < Mg ? ar : (Mg - 1);
      float4 v = *(const float4*)(A + a_off[g] + (long)ar * 2048 + k0 + ks);
      As[ks][m] = v.x; As[ks + 1][m] = v.y; As[ks + 2][m] = v.z; As[ks + 3][m] = v.w;
    }
    {
      int k = t >> 4, n4 = (t & 15) << 2;
      float4 v = *(const float4*)(B + (long)g * 4194304L + (long)(k0 + k) * 2048 + n0 + n4);
      *(float4*)&Bs[k][n4] = v;
    }
    __syncthreads();
#pragma unroll
    for (int k = 0; k < 16; ++k) {
      float a[4], b[4];
#pragma unroll
      for (int i = 0; i < 4; ++i) a[i] = As[k][(ty << 2) + i];
#pragma unroll
      for (int j = 0; j < 4; ++j) b[j] = Bs[k][(tx << 2) + j];
#pragma unroll
      for (int i = 0; i < 4; ++i)
#pragma unroll
        for (int j = 0; j < 4; ++j) acc[i][j] += a[i] * b[j];
    }
  }
  float alg = alpha[g], beg = beta[g];
#pragma unroll
  for (int i = 0; i < 4; ++i) {
    int row = m0 + (ty << 2) + i;
    if (row < Mg) {
#pragma unroll
      for (int j = 0; j < 4; ++j) {
        long idx = a_off[g] + (long)row * 2048 + n0 + (tx << 2) + j;
        Out[idx] = alg * acc[i][j] + beg * Cin[idx];
      }
    }
  }
}

extern "C" void kernel_launch(void* const* d_in, const int* in_sizes, int n_in,
                              void* d_out, int out_size, void* d_ws, size_t ws_size,
                              hipStream_t stream) {
  const float* A = (const float*)d_in[0];
  const float* B = (const float*)d_in[1];
  const float* C = (const float*)d_in[2];
  const float* alpha = (const float*)d_in[3];
  const float* beta = (const float*)d_in[4];
  float* Out = (float*)d_out;

  // ws tiers (ws_size constant across calls -> deterministic, graph-safe)
  if (ws_size >= 268828672ull) {
    u16* ws16 = (u16*)d_ws;
    u16* Bh = ws16;                  // 33,554,432 u16
    u16* Bl = ws16 + 33554432;
    u16* Ah = ws16 + 67108864;       // 33,652,736 u16
    u16* Al = ws16 + 100761600;
    // one dispatch: bid<2048 = B transpose/split, bid>=2048 = A split stream
    prep_fused<<<18480, 256, 0, stream>>>(A, Ah, Al, B, Bh, Bl);
    gemm3<true><<<2064, 256, 0, stream>>>(Ah, Al, nullptr, Bh, Bl, C, Out, alpha, beta);
  } else if (ws_size >= 134217728ull) {
    u16* ws16 = (u16*)d_ws;
    u16* Bh = ws16;
    u16* Bl = ws16 + 33554432;
    prep_fused<<<2048, 256, 0, stream>>>(nullptr, nullptr, nullptr, B, Bh, Bl);
    gemm3<false><<<2064, 256, 0, stream>>>(nullptr, nullptr, A, Bh, Bl, C, Out, alpha, beta);
  } else {
    gemm_naive<<<8224, 256, 0, stream>>>(A, B, C, Out, alpha, beta);
  }
}